// Round 1
// baseline (767.965 us; speedup 1.0000x reference)
//
#include <hip/hip_runtime.h>

#define DIN 64
#define DOUT 64
#define MAXK 32

// ---------------- counting sort by e_kernel (27 bins) ----------------

__global__ void hist_kernel(const int* __restrict__ ek, int E, int* __restrict__ counts) {
    __shared__ int l[MAXK];
    if (threadIdx.x < MAXK) l[threadIdx.x] = 0;
    __syncthreads();
    int stride = gridDim.x * blockDim.x;
    for (int i = blockIdx.x * blockDim.x + threadIdx.x; i < E; i += stride)
        atomicAdd(&l[ek[i]], 1);
    __syncthreads();
    if (threadIdx.x < MAXK) {
        int v = l[threadIdx.x];
        if (v) atomicAdd(&counts[threadIdx.x], v);
    }
}

__global__ void scan_kernel(const int* __restrict__ counts, int K,
                            int* __restrict__ start, int* __restrict__ cursor) {
    if (threadIdx.x == 0 && blockIdx.x == 0) {
        int acc = 0;
        for (int k = 0; k < K; ++k) {
            start[k] = acc;
            cursor[k] = acc;
            acc += counts[k];
        }
    }
}

__global__ void scatter_kernel(const int* __restrict__ ek, int E,
                               int* __restrict__ cursor, int* __restrict__ sorted) {
    __shared__ int lcnt[MAXK], lbase[MAXK], lpos[MAXK];
    if (threadIdx.x < MAXK) { lcnt[threadIdx.x] = 0; lpos[threadIdx.x] = 0; }
    __syncthreads();
    int i = blockIdx.x * blockDim.x + threadIdx.x;
    int k = 0;
    bool valid = (i < E);
    if (valid) { k = ek[i]; atomicAdd(&lcnt[k], 1); }
    __syncthreads();
    if (threadIdx.x < MAXK) {
        int v = lcnt[threadIdx.x];
        if (v) lbase[threadIdx.x] = atomicAdd(&cursor[threadIdx.x], v);
    }
    __syncthreads();
    if (valid) {
        int slot = lbase[k] + atomicAdd(&lpos[k], 1);  // order within bucket irrelevant
        sorted[slot] = i;
    }
}

// ---------------- main compute: one bucket per blockIdx.y ----------------
// Wave holds W[k] in registers: lane owns output column `lane`, wreg[d1] = W[k][d1][lane].
// One edge per wave per iteration; edge metadata + ref row are wave-uniform loads.

__global__ __launch_bounds__(256) void mp_bucket_kernel(
    const float* __restrict__ W, const float* __restrict__ ref,
    const int* __restrict__ e_ref, const int* __restrict__ e_query,
    const float* __restrict__ e_weight, const int* __restrict__ sorted,
    const int* __restrict__ start, const int* __restrict__ counts,
    float* __restrict__ out)
{
    const int k = blockIdx.y;
    const int lane = threadIdx.x & 63;
    const int wid = threadIdx.x >> 6;

    float wreg[DIN];
    const float* Wk = W + k * DIN * DOUT;
    #pragma unroll
    for (int d = 0; d < DIN; ++d) wreg[d] = Wk[d * DOUT + lane];   // coalesced across lanes

    const int s = start[k];
    const int c = counts[k];
    const int nwaves = gridDim.x * 4;

    for (int i = blockIdx.x * 4 + wid; i < c; i += nwaves) {
        int eid = __builtin_amdgcn_readfirstlane(sorted[s + i]);   // force wave-uniform
        int r = e_ref[eid];
        int q = e_query[eid];
        float w = e_weight[eid];
        const float* row = ref + r * DIN;                          // uniform address -> scalar path

        float a0 = 0.f, a1 = 0.f, a2 = 0.f, a3 = 0.f;
        #pragma unroll
        for (int d = 0; d < DIN; d += 4) {
            a0 += row[d + 0] * wreg[d + 0];
            a1 += row[d + 1] * wreg[d + 1];
            a2 += row[d + 2] * wreg[d + 2];
            a3 += row[d + 3] * wreg[d + 3];
        }
        float v = ((a0 + a1) + (a2 + a3)) * w;
        atomicAdd(&out[q * DOUT + lane], v);                       // 64 consecutive floats
    }
}

// ---------------- fallback (no workspace): unsorted, weights from cache ----------------

__global__ __launch_bounds__(256) void mp_naive_kernel(
    const float* __restrict__ W, const float* __restrict__ ref,
    const int* __restrict__ e_kernel, const int* __restrict__ e_ref,
    const int* __restrict__ e_query, const float* __restrict__ e_weight,
    float* __restrict__ out, int E)
{
    const int lane = threadIdx.x & 63;
    int gw = (blockIdx.x * blockDim.x + threadIdx.x) >> 6;
    int nw = (gridDim.x * blockDim.x) >> 6;
    for (int e = gw; e < E; e += nw) {
        int k = __builtin_amdgcn_readfirstlane(e_kernel[e]);
        int r = e_ref[e];
        int q = e_query[e];
        float w = e_weight[e];
        const float* row = ref + r * DIN;
        const float* Wk = W + k * DIN * DOUT;
        float a0 = 0.f, a1 = 0.f, a2 = 0.f, a3 = 0.f;
        #pragma unroll
        for (int d = 0; d < DIN; d += 4) {
            a0 += row[d + 0] * Wk[(d + 0) * DOUT + lane];
            a1 += row[d + 1] * Wk[(d + 1) * DOUT + lane];
            a2 += row[d + 2] * Wk[(d + 2) * DOUT + lane];
            a3 += row[d + 3] * Wk[(d + 3) * DOUT + lane];
        }
        atomicAdd(&out[q * DOUT + lane], ((a0 + a1) + (a2 + a3)) * w);
    }
}

extern "C" void kernel_launch(void* const* d_in, const int* in_sizes, int n_in,
                              void* d_out, int out_size, void* d_ws, size_t ws_size,
                              hipStream_t stream) {
    const float* W        = (const float*)d_in[0];   // [K0, 64, 64]
    const float* ref      = (const float*)d_in[1];   // [N, 64]
    const int*   e_kernel = (const int*)d_in[2];     // [E]
    const int*   e_ref    = (const int*)d_in[3];     // [E]
    const int*   e_query  = (const int*)d_in[4];     // [E]
    // d_in[5] = num_queries (scalar on device; M derived from out_size instead)
    const float* e_weight = (const float*)d_in[6];   // [E]

    const int K0 = in_sizes[0] / (DIN * DOUT);       // 27
    const int E  = in_sizes[2];

    float* out = (float*)d_out;

    // output is accumulated via atomics -> zero it (harness poisons with 0xAA)
    hipMemsetAsync(out, 0, (size_t)out_size * sizeof(float), stream);

    size_t need = (size_t)(96 + E) * sizeof(int);
    if (ws_size >= need) {
        int* ws_i   = (int*)d_ws;
        int* counts = ws_i;          // [32]
        int* start  = ws_i + 32;     // [32]
        int* cursor = ws_i + 64;     // [32]
        int* sorted = ws_i + 96;     // [E]

        hipMemsetAsync(counts, 0, 96 * sizeof(int), stream);

        hist_kernel<<<512, 256, 0, stream>>>(e_kernel, E, counts);
        scan_kernel<<<1, 64, 0, stream>>>(counts, K0, start, cursor);
        scatter_kernel<<<(E + 255) / 256, 256, 0, stream>>>(e_kernel, E, cursor, sorted);

        dim3 grid(64, K0);
        mp_bucket_kernel<<<grid, 256, 0, stream>>>(W, ref, e_ref, e_query, e_weight,
                                                   sorted, start, counts, out);
    } else {
        mp_naive_kernel<<<4096, 256, 0, stream>>>(W, ref, e_kernel, e_ref, e_query,
                                                  e_weight, out, E);
    }
}

// Round 2
// 479.627 us; speedup vs baseline: 1.6012x; 1.6012x over previous
//
#include <hip/hip_runtime.h>

#define DIN 64
#define DOUT 64
#define MAXK 32

typedef __bf16 bf16x8 __attribute__((ext_vector_type(8)));
typedef float  f32x4  __attribute__((ext_vector_type(4)));

static __device__ inline unsigned short f2b(float x) {
    return __builtin_bit_cast(unsigned short, (__bf16)x);
}
static __device__ inline float b2f(unsigned short u) {
    return __uint_as_float(((unsigned int)u) << 16);
}

// ---------------- conversions ----------------

__global__ void conv_ref_kernel(const float* __restrict__ src,
                                unsigned short* __restrict__ dst, int n) {
    int i = blockIdx.x * blockDim.x + threadIdx.x;
    if (i < n) dst[i] = f2b(src[i]);
}

// W[k][d1][d2] fp32 -> Wt[k][d2][d1] bf16 (transposed for MFMA B-frag contiguity)
__global__ void conv_w_kernel(const float* __restrict__ W,
                              unsigned short* __restrict__ Wt, int total) {
    int i = blockIdx.x * blockDim.x + threadIdx.x;
    if (i < total) {
        int d1 = i & 63;
        int d2 = (i >> 6) & 63;
        int k  = i >> 12;
        Wt[i] = f2b(W[(k * 64 + d1) * 64 + d2]);
    }
}

// ---------------- Phase A: dense transform GEMM (bf16 MFMA) ----------------
// transformed[n][k*64+d2] = sum_d1 ref[n][d1] * W[k][d1][d2]
// Each wave: 16 rows of A (held in 2 k-frags), loops K0 kernels, 8 MFMAs each.

__global__ __launch_bounds__(256) void phaseA_kernel(
    const unsigned short* __restrict__ refb,   // [N][64] bf16
    const unsigned short* __restrict__ Wt,     // [K0][64 d2][64 d1] bf16
    unsigned short* __restrict__ T,            // [N][K0*64] bf16
    int K0)
{
    const int lane = threadIdx.x & 63;
    const int wid  = threadIdx.x >> 6;
    const int m0   = blockIdx.x * 64 + wid * 16;
    const int col  = lane & 15;
    const int quad = lane >> 4;
    const int KD   = K0 * 64;

    // A frags: lane holds A[m=lane&15][k = quad*8 + j]
    const int arow = m0 + col;
    bf16x8 a0 = *reinterpret_cast<const bf16x8*>(refb + (size_t)arow * 64 + quad * 8);
    bf16x8 a1 = *reinterpret_cast<const bf16x8*>(refb + (size_t)arow * 64 + 32 + quad * 8);

    for (int k = 0; k < K0; ++k) {
        const unsigned short* Wk = Wt + (size_t)k * 64 * 64;
        f32x4 acc[4];
        #pragma unroll
        for (int t = 0; t < 4; ++t) {
            // B frag: lane holds B[kk = s + quad*8 + j][n = t*16 + (lane&15)]
            // stored as Wt[n][kk] -> contiguous 8 bf16
            const unsigned short* bp = Wk + (size_t)(t * 16 + col) * 64 + quad * 8;
            bf16x8 b0 = *reinterpret_cast<const bf16x8*>(bp);
            bf16x8 b1 = *reinterpret_cast<const bf16x8*>(bp + 32);
            f32x4 c = {0.f, 0.f, 0.f, 0.f};
            c = __builtin_amdgcn_mfma_f32_16x16x32_bf16(a0, b0, c, 0, 0, 0);
            c = __builtin_amdgcn_mfma_f32_16x16x32_bf16(a1, b1, c, 0, 0, 0);
            acc[t] = c;
        }
        // C/D layout: col = lane&15, row = quad*4 + reg
        size_t base = (size_t)(m0 + quad * 4) * KD + k * 64 + col;
        #pragma unroll
        for (int t = 0; t < 4; ++t) {
            #pragma unroll
            for (int r = 0; r < 4; ++r) {
                T[base + (size_t)r * KD + t * 16] = f2b(acc[t][r]);
            }
        }
    }
}

// ---------------- query counting sort ----------------

__global__ void qhist_kernel(const int* __restrict__ eq, int E, int* __restrict__ qcount) {
    int stride = gridDim.x * blockDim.x;
    for (int i = blockIdx.x * blockDim.x + threadIdx.x; i < E; i += stride)
        atomicAdd(&qcount[eq[i]], 1);
}

__global__ void scan1_kernel(const int* __restrict__ qcount, int* __restrict__ qstart,
                             int* __restrict__ bsum) {
    __shared__ int sh[256];
    int t = threadIdx.x;
    int gid = blockIdx.x * 256 + t;
    int v = qcount[gid];
    sh[t] = v;
    __syncthreads();
    #pragma unroll
    for (int o = 1; o < 256; o <<= 1) {
        int x = (t >= o) ? sh[t - o] : 0;
        __syncthreads();
        sh[t] += x;
        __syncthreads();
    }
    qstart[gid] = sh[t] - v;                 // exclusive within block
    if (t == 255) bsum[blockIdx.x] = sh[255];
}

__global__ void scan2_kernel(int* __restrict__ bsum, int nb) {
    __shared__ int sh[256];
    int t = threadIdx.x;
    int v = (t < nb) ? bsum[t] : 0;
    sh[t] = v;
    __syncthreads();
    #pragma unroll
    for (int o = 1; o < 256; o <<= 1) {
        int x = (t >= o) ? sh[t - o] : 0;
        __syncthreads();
        sh[t] += x;
        __syncthreads();
    }
    if (t < nb) bsum[t] = sh[t] - v;         // exclusive block offsets
}

__global__ void scan3_kernel(int* __restrict__ qstart, int* __restrict__ qcursor,
                             const int* __restrict__ bsum, int M, int E) {
    int gid = blockIdx.x * 256 + threadIdx.x;
    int v = qstart[gid] + bsum[blockIdx.x];
    qstart[gid] = v;
    qcursor[gid] = v;
    if (gid == 0) qstart[M] = E;
}

// build per-edge records in query-sorted order: {e_ref, e_kernel, w_bits, 0}
__global__ void qscatter_kernel(const int* __restrict__ eq, const int* __restrict__ er,
                                const int* __restrict__ ek, const float* __restrict__ ew,
                                int E, int* __restrict__ qcursor, int4* __restrict__ rec) {
    int i = blockIdx.x * blockDim.x + threadIdx.x;
    if (i < E) {
        int q = eq[i];
        int slot = atomicAdd(&qcursor[q], 1);
        rec[slot] = make_int4(er[i], ek[i], __float_as_int(ew[i]), 0);
    }
}

// ---------------- Phase B: per-query gather-accumulate (no atomics) ----------------

__global__ __launch_bounds__(256) void phaseB_kernel(
    const unsigned short* __restrict__ T,    // [N][KD] bf16
    const int4* __restrict__ rec,
    const int* __restrict__ qstart,
    float* __restrict__ out, int KD)
{
    const int lane = threadIdx.x & 63;
    const int wid  = threadIdx.x >> 6;
    const int q    = blockIdx.x * 4 + wid;

    int beg = qstart[q];
    int end = qstart[q + 1];
    float acc = 0.f;

    int j = beg;
    for (; j + 1 < end; j += 2) {
        int4 v0 = rec[j];
        int4 v1 = rec[j + 1];
        int r0 = __builtin_amdgcn_readfirstlane(v0.x);
        int k0 = __builtin_amdgcn_readfirstlane(v0.y);
        float w0 = __uint_as_float(__builtin_amdgcn_readfirstlane(v0.z));
        int r1 = __builtin_amdgcn_readfirstlane(v1.x);
        int k1 = __builtin_amdgcn_readfirstlane(v1.y);
        float w1 = __uint_as_float(__builtin_amdgcn_readfirstlane(v1.z));
        unsigned short t0 = T[(size_t)r0 * KD + k0 * 64 + lane];
        unsigned short t1 = T[(size_t)r1 * KD + k1 * 64 + lane];
        acc += w0 * b2f(t0);
        acc += w1 * b2f(t1);
    }
    if (j < end) {
        int4 v0 = rec[j];
        int r0 = __builtin_amdgcn_readfirstlane(v0.x);
        int k0 = __builtin_amdgcn_readfirstlane(v0.y);
        float w0 = __uint_as_float(__builtin_amdgcn_readfirstlane(v0.z));
        acc += w0 * b2f(T[(size_t)r0 * KD + k0 * 64 + lane]);
    }
    out[(size_t)q * 64 + lane] = acc;
}

// ================= fallback path (round-1): kernel-bucketed fp32 =================

__global__ void hist_kernel(const int* __restrict__ ek, int E, int* __restrict__ counts) {
    __shared__ int l[MAXK];
    if (threadIdx.x < MAXK) l[threadIdx.x] = 0;
    __syncthreads();
    int stride = gridDim.x * blockDim.x;
    for (int i = blockIdx.x * blockDim.x + threadIdx.x; i < E; i += stride)
        atomicAdd(&l[ek[i]], 1);
    __syncthreads();
    if (threadIdx.x < MAXK) {
        int v = l[threadIdx.x];
        if (v) atomicAdd(&counts[threadIdx.x], v);
    }
}

__global__ void scan_kernel(const int* __restrict__ counts, int K,
                            int* __restrict__ start, int* __restrict__ cursor) {
    if (threadIdx.x == 0 && blockIdx.x == 0) {
        int acc = 0;
        for (int k = 0; k < K; ++k) {
            start[k] = acc;
            cursor[k] = acc;
            acc += counts[k];
        }
    }
}

__global__ void scatter_kernel(const int* __restrict__ ek, int E,
                               int* __restrict__ cursor, int* __restrict__ sorted) {
    __shared__ int lcnt[MAXK], lbase[MAXK], lpos[MAXK];
    if (threadIdx.x < MAXK) { lcnt[threadIdx.x] = 0; lpos[threadIdx.x] = 0; }
    __syncthreads();
    int i = blockIdx.x * blockDim.x + threadIdx.x;
    int k = 0;
    bool valid = (i < E);
    if (valid) { k = ek[i]; atomicAdd(&lcnt[k], 1); }
    __syncthreads();
    if (threadIdx.x < MAXK) {
        int v = lcnt[threadIdx.x];
        if (v) lbase[threadIdx.x] = atomicAdd(&cursor[threadIdx.x], v);
    }
    __syncthreads();
    if (valid) {
        int slot = lbase[k] + atomicAdd(&lpos[k], 1);
        sorted[slot] = i;
    }
}

__global__ __launch_bounds__(256) void mp_bucket_kernel(
    const float* __restrict__ W, const float* __restrict__ ref,
    const int* __restrict__ e_ref, const int* __restrict__ e_query,
    const float* __restrict__ e_weight, const int* __restrict__ sorted,
    const int* __restrict__ start, const int* __restrict__ counts,
    float* __restrict__ out)
{
    const int k = blockIdx.y;
    const int lane = threadIdx.x & 63;
    const int wid = threadIdx.x >> 6;

    float wreg[DIN];
    const float* Wk = W + k * DIN * DOUT;
    #pragma unroll
    for (int d = 0; d < DIN; ++d) wreg[d] = Wk[d * DOUT + lane];

    const int s = start[k];
    const int c = counts[k];
    const int nwaves = gridDim.x * 4;

    for (int i = blockIdx.x * 4 + wid; i < c; i += nwaves) {
        int eid = __builtin_amdgcn_readfirstlane(sorted[s + i]);
        int r = e_ref[eid];
        int q = e_query[eid];
        float w = e_weight[eid];
        const float* row = ref + r * DIN;
        float a0 = 0.f, a1 = 0.f, a2 = 0.f, a3 = 0.f;
        #pragma unroll
        for (int d = 0; d < DIN; d += 4) {
            a0 += row[d + 0] * wreg[d + 0];
            a1 += row[d + 1] * wreg[d + 1];
            a2 += row[d + 2] * wreg[d + 2];
            a3 += row[d + 3] * wreg[d + 3];
        }
        atomicAdd(&out[q * DOUT + lane], ((a0 + a1) + (a2 + a3)) * w);
    }
}

// =================================================================================

extern "C" void kernel_launch(void* const* d_in, const int* in_sizes, int n_in,
                              void* d_out, int out_size, void* d_ws, size_t ws_size,
                              hipStream_t stream) {
    const float* W        = (const float*)d_in[0];   // [K0, 64, 64]
    const float* ref      = (const float*)d_in[1];   // [N, 64]
    const int*   e_kernel = (const int*)d_in[2];     // [E]
    const int*   e_ref    = (const int*)d_in[3];     // [E]
    const int*   e_query  = (const int*)d_in[4];     // [E]
    const float* e_weight = (const float*)d_in[6];   // [E]

    const int K0 = in_sizes[0] / (DIN * DOUT);
    const int N  = in_sizes[1] / DIN;
    const int E  = in_sizes[2];
    const int M  = out_size / DOUT;
    const int KD = K0 * 64;

    float* out = (float*)d_out;

    // ---- plan A workspace carve ----
    size_t off = 0;
    auto alloc = [&](size_t bytes, size_t align) {
        off = (off + align - 1) / align * align;
        size_t r = off; off += bytes; return r;
    };
    size_t o_rec     = alloc((size_t)E * 16, 16);
    size_t o_qstart  = alloc((size_t)(M + 1) * 4, 4);
    size_t o_qcursor = alloc((size_t)M * 4, 4);
    size_t o_bsum    = alloc(1024 * 4, 4);
    size_t o_wt      = alloc((size_t)K0 * 4096 * 2, 16);
    size_t o_refb    = alloc((size_t)N * 64 * 2, 16);
    size_t o_T       = alloc((size_t)N * KD * 2, 16);
    size_t needA = off;

    int nb = (M + 255) / 256;   // scan blocks
    bool planA_ok = (ws_size >= needA) && (M % 256 == 0) && (nb <= 256) &&
                    (N % 64 == 0) && (K0 <= 64);

    if (planA_ok) {
        char* ws = (char*)d_ws;
        int4* rec            = (int4*)(ws + o_rec);
        int*  qstart         = (int*)(ws + o_qstart);
        int*  qcursor        = (int*)(ws + o_qcursor);
        int*  bsum           = (int*)(ws + o_bsum);
        unsigned short* Wt   = (unsigned short*)(ws + o_wt);
        unsigned short* refb = (unsigned short*)(ws + o_refb);
        unsigned short* T    = (unsigned short*)(ws + o_T);

        // conversions
        conv_ref_kernel<<<(N * 64 + 255) / 256, 256, 0, stream>>>(ref, refb, N * 64);
        conv_w_kernel<<<(K0 * 4096 + 255) / 256, 256, 0, stream>>>(W, Wt, K0 * 4096);

        // query counting sort (qcursor doubles as qcount for the hist)
        hipMemsetAsync(qcursor, 0, (size_t)M * 4, stream);
        qhist_kernel<<<1024, 256, 0, stream>>>(e_query, E, qcursor);
        scan1_kernel<<<nb, 256, 0, stream>>>(qcursor, qstart, bsum);
        scan2_kernel<<<1, 256, 0, stream>>>(bsum, nb);
        scan3_kernel<<<nb, 256, 0, stream>>>(qstart, qcursor, bsum, M, E);
        qscatter_kernel<<<(E + 255) / 256, 256, 0, stream>>>(e_query, e_ref, e_kernel,
                                                             e_weight, E, qcursor, rec);

        // dense transform (independent of the sort; same stream serializes fine)
        phaseA_kernel<<<N / 64, 256, 0, stream>>>(refb, Wt, T, K0);

        // gather-accumulate, one wave per query, single write per output row
        phaseB_kernel<<<M / 4, 256, 0, stream>>>(T, rec, qstart, out, KD);
    } else {
        // fallback: round-1 kernel-bucketed fp32 path
        hipMemsetAsync(out, 0, (size_t)out_size * sizeof(float), stream);
        size_t needB = (size_t)(96 + E) * sizeof(int);
        if (ws_size >= needB) {
            int* ws_i   = (int*)d_ws;
            int* counts = ws_i;
            int* start  = ws_i + 32;
            int* cursor = ws_i + 64;
            int* sorted = ws_i + 96;
            hipMemsetAsync(counts, 0, 96 * sizeof(int), stream);
            hist_kernel<<<512, 256, 0, stream>>>(e_kernel, E, counts);
            scan_kernel<<<1, 64, 0, stream>>>(counts, K0, start, cursor);
            scatter_kernel<<<(E + 255) / 256, 256, 0, stream>>>(e_kernel, E, cursor, sorted);
            dim3 grid(64, K0);
            mp_bucket_kernel<<<grid, 256, 0, stream>>>(W, ref, e_ref, e_query, e_weight,
                                                       sorted, start, counts, out);
        }
    }
}

// Round 3
// 449.286 us; speedup vs baseline: 1.7093x; 1.0675x over previous
//
#include <hip/hip_runtime.h>

#define DIN 64
#define DOUT 64
#define MAXK 32

typedef __bf16 bf16x8 __attribute__((ext_vector_type(8)));
typedef float  f32x4  __attribute__((ext_vector_type(4)));

static __device__ inline unsigned short f2b(float x) {
    return __builtin_bit_cast(unsigned short, (__bf16)x);
}
static __device__ inline float b2f(unsigned short u) {
    return __uint_as_float(((unsigned int)u) << 16);
}

// ---------------- conversions ----------------

// W[k][d1][d2] fp32 -> Wt[k][d2][d1] bf16 (transposed: contiguous in d1)
__global__ void conv_w_kernel(const float* __restrict__ W,
                              unsigned short* __restrict__ Wt, int total) {
    int i = blockIdx.x * blockDim.x + threadIdx.x;
    if (i < total) {
        int d1 = i & 63;
        int d2 = (i >> 6) & 63;
        int k  = i >> 12;
        Wt[i] = f2b(W[(k * 64 + d1) * 64 + d2]);
    }
}

// ---------------- Phase A: dense transform GEMM (bf16 MFMA) ----------------
// T[n][k*64+d2] = sum_d1 ref[n][d1] * W[k][d1][d2]
// MFMA roles: A = W^T (M=d2, K=d1), B = ref (K=d1, N=n). C layout: col=lane&15 -> n,
// row=quad*4+reg -> d2, so each lane's 4 regs are 4 CONSECUTIVE d2 -> 8B packed store.

__global__ __launch_bounds__(256) void phaseA_kernel(
    const float* __restrict__ ref,             // [N][64] fp32
    const unsigned short* __restrict__ Wt,     // [K0][d2][d1] bf16
    unsigned short* __restrict__ T,            // [N][K0*64] bf16
    int K0, int KPER)
{
    const int lane = threadIdx.x & 63;
    const int wid  = threadIdx.x >> 6;
    const int col  = lane & 15;
    const int quad = lane >> 4;
    const int n0   = blockIdx.x * 64 + wid * 16;
    const int row  = n0 + col;
    const int KD   = K0 * 64;

    // B frag (resident across k-loop): lane holds ref[row][d1 = quad*8 + j]
    const float* rp = ref + (size_t)row * 64;
    f32x4 r0 = *reinterpret_cast<const f32x4*>(rp + quad * 8);
    f32x4 r1 = *reinterpret_cast<const f32x4*>(rp + quad * 8 + 4);
    f32x4 r2 = *reinterpret_cast<const f32x4*>(rp + 32 + quad * 8);
    f32x4 r3 = *reinterpret_cast<const f32x4*>(rp + 32 + quad * 8 + 4);
    bf16x8 b0, b1;
    #pragma unroll
    for (int i = 0; i < 4; ++i) {
        b0[i]     = (__bf16)r0[i];
        b0[4 + i] = (__bf16)r1[i];
        b1[i]     = (__bf16)r2[i];
        b1[4 + i] = (__bf16)r3[i];
    }

    int kbeg = blockIdx.y * KPER;
    int kend = kbeg + KPER; if (kend > K0) kend = K0;

    for (int k = kbeg; k < kend; ++k) {
        const unsigned short* Wk = Wt + (size_t)k * 4096;
        #pragma unroll
        for (int t = 0; t < 4; ++t) {
            // A frag: lane holds W^T[m = t*16+col][d1 = quad*8 + j] = Wt[t*16+col][quad*8+j]
            const unsigned short* ap = Wk + (size_t)(t * 16 + col) * 64 + quad * 8;
            bf16x8 a0 = *reinterpret_cast<const bf16x8*>(ap);
            bf16x8 a1 = *reinterpret_cast<const bf16x8*>(ap + 32);
            f32x4 c = {0.f, 0.f, 0.f, 0.f};
            c = __builtin_amdgcn_mfma_f32_16x16x32_bf16(a0, b0, c, 0, 0, 0);
            c = __builtin_amdgcn_mfma_f32_16x16x32_bf16(a1, b1, c, 0, 0, 0);
            // lane holds T[row][k*64 + t*16 + quad*4 + {0,1,2,3}] -> one 8B store
            unsigned int lo = (unsigned int)f2b(c[0]) | ((unsigned int)f2b(c[1]) << 16);
            unsigned int hi = (unsigned int)f2b(c[2]) | ((unsigned int)f2b(c[3]) << 16);
            size_t off = (size_t)row * KD + k * 64 + t * 16 + quad * 4;
            *reinterpret_cast<uint2*>(T + off) = make_uint2(lo, hi);
        }
    }
}

// ---------------- query counting sort ----------------

__global__ void qhist_kernel(const int* __restrict__ eq, int E, int* __restrict__ qcount) {
    int stride = gridDim.x * blockDim.x;
    for (int i = blockIdx.x * blockDim.x + threadIdx.x; i < E; i += stride)
        atomicAdd(&qcount[eq[i]], 1);
}

__global__ void scan1_kernel(const int* __restrict__ qcount, int* __restrict__ qstart,
                             int* __restrict__ bsum) {
    __shared__ int sh[256];
    int t = threadIdx.x;
    int gid = blockIdx.x * 256 + t;
    int v = qcount[gid];
    sh[t] = v;
    __syncthreads();
    #pragma unroll
    for (int o = 1; o < 256; o <<= 1) {
        int x = (t >= o) ? sh[t - o] : 0;
        __syncthreads();
        sh[t] += x;
        __syncthreads();
    }
    qstart[gid] = sh[t] - v;
    if (t == 255) bsum[blockIdx.x] = sh[255];
}

__global__ void scan2_kernel(int* __restrict__ bsum, int nb) {
    __shared__ int sh[256];
    int t = threadIdx.x;
    int v = (t < nb) ? bsum[t] : 0;
    sh[t] = v;
    __syncthreads();
    #pragma unroll
    for (int o = 1; o < 256; o <<= 1) {
        int x = (t >= o) ? sh[t - o] : 0;
        __syncthreads();
        sh[t] += x;
        __syncthreads();
    }
    if (t < nb) bsum[t] = sh[t] - v;
}

__global__ void scan3_kernel(int* __restrict__ qstart, int* __restrict__ qcursor,
                             const int* __restrict__ bsum, int M, int E) {
    int gid = blockIdx.x * 256 + threadIdx.x;
    int v = qstart[gid] + bsum[blockIdx.x];
    qstart[gid] = v;
    qcursor[gid] = v;
    if (gid == 0) qstart[M] = E;
}

// build per-edge records in query-sorted order, packed 8B: {r | k<<16, w_bits}
__global__ void qscatter_kernel(const int* __restrict__ eq, const int* __restrict__ er,
                                const int* __restrict__ ek, const float* __restrict__ ew,
                                int E, int* __restrict__ qcursor, uint2* __restrict__ rec) {
    int i = blockIdx.x * blockDim.x + threadIdx.x;
    if (i < E) {
        int q = eq[i];
        int slot = atomicAdd(&qcursor[q], 1);
        rec[slot] = make_uint2((unsigned int)er[i] | ((unsigned int)ek[i] << 16),
                               __float_as_uint(ew[i]));
    }
}

// ---------------- Phase B: per-query gather-accumulate (no atomics) ----------------

__global__ __launch_bounds__(256) void phaseB_kernel(
    const unsigned short* __restrict__ T,    // [N][KD] bf16
    const uint2* __restrict__ rec,
    const int* __restrict__ qstart,
    float* __restrict__ out, int KD)
{
    const int lane = threadIdx.x & 63;
    const int wid  = threadIdx.x >> 6;
    const int q    = blockIdx.x * 4 + wid;

    int beg = qstart[q];
    int end = qstart[q + 1];
    float acc = 0.f;

    int j = beg;
    for (; j + 3 < end; j += 4) {
        uint2 v0 = rec[j];
        uint2 v1 = rec[j + 1];
        uint2 v2 = rec[j + 2];
        uint2 v3 = rec[j + 3];
        unsigned m0 = __builtin_amdgcn_readfirstlane(v0.x);
        unsigned m1 = __builtin_amdgcn_readfirstlane(v1.x);
        unsigned m2 = __builtin_amdgcn_readfirstlane(v2.x);
        unsigned m3 = __builtin_amdgcn_readfirstlane(v3.x);
        float w0 = __uint_as_float(__builtin_amdgcn_readfirstlane(v0.y));
        float w1 = __uint_as_float(__builtin_amdgcn_readfirstlane(v1.y));
        float w2 = __uint_as_float(__builtin_amdgcn_readfirstlane(v2.y));
        float w3 = __uint_as_float(__builtin_amdgcn_readfirstlane(v3.y));
        unsigned short t0 = T[(size_t)(m0 & 0xFFFFu) * KD + (m0 >> 16) * 64 + lane];
        unsigned short t1 = T[(size_t)(m1 & 0xFFFFu) * KD + (m1 >> 16) * 64 + lane];
        unsigned short t2 = T[(size_t)(m2 & 0xFFFFu) * KD + (m2 >> 16) * 64 + lane];
        unsigned short t3 = T[(size_t)(m3 & 0xFFFFu) * KD + (m3 >> 16) * 64 + lane];
        acc = fmaf(w0, b2f(t0), acc);
        acc = fmaf(w1, b2f(t1), acc);
        acc = fmaf(w2, b2f(t2), acc);
        acc = fmaf(w3, b2f(t3), acc);
    }
    for (; j < end; ++j) {
        uint2 v0 = rec[j];
        unsigned m0 = __builtin_amdgcn_readfirstlane(v0.x);
        float w0 = __uint_as_float(__builtin_amdgcn_readfirstlane(v0.y));
        acc = fmaf(w0, b2f(T[(size_t)(m0 & 0xFFFFu) * KD + (m0 >> 16) * 64 + lane]), acc);
    }
    out[(size_t)q * 64 + lane] = acc;
}

// ================= fallback path (round-1): kernel-bucketed fp32 =================

__global__ void hist_kernel(const int* __restrict__ ek, int E, int* __restrict__ counts) {
    __shared__ int l[MAXK];
    if (threadIdx.x < MAXK) l[threadIdx.x] = 0;
    __syncthreads();
    int stride = gridDim.x * blockDim.x;
    for (int i = blockIdx.x * blockDim.x + threadIdx.x; i < E; i += stride)
        atomicAdd(&l[ek[i]], 1);
    __syncthreads();
    if (threadIdx.x < MAXK) {
        int v = l[threadIdx.x];
        if (v) atomicAdd(&counts[threadIdx.x], v);
    }
}

__global__ void scan_kernel(const int* __restrict__ counts, int K,
                            int* __restrict__ start, int* __restrict__ cursor) {
    if (threadIdx.x == 0 && blockIdx.x == 0) {
        int acc = 0;
        for (int k = 0; k < K; ++k) {
            start[k] = acc;
            cursor[k] = acc;
            acc += counts[k];
        }
    }
}

__global__ void scatter_kernel(const int* __restrict__ ek, int E,
                               int* __restrict__ cursor, int* __restrict__ sorted) {
    __shared__ int lcnt[MAXK], lbase[MAXK], lpos[MAXK];
    if (threadIdx.x < MAXK) { lcnt[threadIdx.x] = 0; lpos[threadIdx.x] = 0; }
    __syncthreads();
    int i = blockIdx.x * blockDim.x + threadIdx.x;
    int k = 0;
    bool valid = (i < E);
    if (valid) { k = ek[i]; atomicAdd(&lcnt[k], 1); }
    __syncthreads();
    if (threadIdx.x < MAXK) {
        int v = lcnt[threadIdx.x];
        if (v) lbase[threadIdx.x] = atomicAdd(&cursor[threadIdx.x], v);
    }
    __syncthreads();
    if (valid) {
        int slot = lbase[k] + atomicAdd(&lpos[k], 1);
        sorted[slot] = i;
    }
}

__global__ __launch_bounds__(256) void mp_bucket_kernel(
    const float* __restrict__ W, const float* __restrict__ ref,
    const int* __restrict__ e_ref, const int* __restrict__ e_query,
    const float* __restrict__ e_weight, const int* __restrict__ sorted,
    const int* __restrict__ start, const int* __restrict__ counts,
    float* __restrict__ out)
{
    const int k = blockIdx.y;
    const int lane = threadIdx.x & 63;
    const int wid = threadIdx.x >> 6;

    float wreg[DIN];
    const float* Wk = W + k * DIN * DOUT;
    #pragma unroll
    for (int d = 0; d < DIN; ++d) wreg[d] = Wk[d * DOUT + lane];

    const int s = start[k];
    const int c = counts[k];
    const int nwaves = gridDim.x * 4;

    for (int i = blockIdx.x * 4 + wid; i < c; i += nwaves) {
        int eid = __builtin_amdgcn_readfirstlane(sorted[s + i]);
        int r = e_ref[eid];
        int q = e_query[eid];
        float w = e_weight[eid];
        const float* row = ref + r * DIN;
        float a0 = 0.f, a1 = 0.f, a2 = 0.f, a3 = 0.f;
        #pragma unroll
        for (int d = 0; d < DIN; d += 4) {
            a0 += row[d + 0] * wreg[d + 0];
            a1 += row[d + 1] * wreg[d + 1];
            a2 += row[d + 2] * wreg[d + 2];
            a3 += row[d + 3] * wreg[d + 3];
        }
        atomicAdd(&out[q * DOUT + lane], ((a0 + a1) + (a2 + a3)) * w);
    }
}

// =================================================================================

extern "C" void kernel_launch(void* const* d_in, const int* in_sizes, int n_in,
                              void* d_out, int out_size, void* d_ws, size_t ws_size,
                              hipStream_t stream) {
    const float* W        = (const float*)d_in[0];   // [K0, 64, 64]
    const float* ref      = (const float*)d_in[1];   // [N, 64]
    const int*   e_kernel = (const int*)d_in[2];     // [E]
    const int*   e_ref    = (const int*)d_in[3];     // [E]
    const int*   e_query  = (const int*)d_in[4];     // [E]
    const float* e_weight = (const float*)d_in[6];   // [E]

    const int K0 = in_sizes[0] / (DIN * DOUT);
    const int N  = in_sizes[1] / DIN;
    const int E  = in_sizes[2];
    const int M  = out_size / DOUT;
    const int KD = K0 * 64;

    float* out = (float*)d_out;

    // ---- plan A workspace carve ----
    size_t off = 0;
    auto alloc = [&](size_t bytes, size_t align) {
        off = (off + align - 1) / align * align;
        size_t r = off; off += bytes; return r;
    };
    size_t o_rec     = alloc((size_t)E * 8, 16);
    size_t o_qstart  = alloc((size_t)(M + 1) * 4, 4);
    size_t o_qcursor = alloc((size_t)M * 4, 4);
    size_t o_bsum    = alloc(1024 * 4, 4);
    size_t o_wt      = alloc((size_t)K0 * 4096 * 2, 16);
    size_t o_T       = alloc((size_t)N * KD * 2, 16);
    size_t needA = off;

    int nb = (M + 255) / 256;
    bool planA_ok = (ws_size >= needA) && (M % 256 == 0) && (nb <= 256) &&
                    (N % 64 == 0) && (N <= 65536) && (K0 <= 64);

    if (planA_ok) {
        char* ws = (char*)d_ws;
        uint2* rec           = (uint2*)(ws + o_rec);
        int*  qstart         = (int*)(ws + o_qstart);
        int*  qcursor        = (int*)(ws + o_qcursor);
        int*  bsum           = (int*)(ws + o_bsum);
        unsigned short* Wt   = (unsigned short*)(ws + o_wt);
        unsigned short* T    = (unsigned short*)(ws + o_T);

        conv_w_kernel<<<(K0 * 4096 + 255) / 256, 256, 0, stream>>>(W, Wt, K0 * 4096);

        hipMemsetAsync(qcursor, 0, (size_t)M * 4, stream);
        qhist_kernel<<<1024, 256, 0, stream>>>(e_query, E, qcursor);
        scan1_kernel<<<nb, 256, 0, stream>>>(qcursor, qstart, bsum);
        scan2_kernel<<<1, 256, 0, stream>>>(bsum, nb);
        scan3_kernel<<<nb, 256, 0, stream>>>(qstart, qcursor, bsum, M, E);
        qscatter_kernel<<<(E + 255) / 256, 256, 0, stream>>>(e_query, e_ref, e_kernel,
                                                             e_weight, E, qcursor, rec);

        // k-split over grid.y for occupancy; KPER = ceil(K0/3)
        int ksplit = 3;
        int KPER = (K0 + ksplit - 1) / ksplit;
        dim3 gridA(N / 64, ksplit);
        phaseA_kernel<<<gridA, 256, 0, stream>>>(ref, Wt, T, K0, KPER);

        phaseB_kernel<<<M / 4, 256, 0, stream>>>(T, rec, qstart, out, KD);
    } else {
        hipMemsetAsync(out, 0, (size_t)out_size * sizeof(float), stream);
        size_t needB = (size_t)(96 + E) * sizeof(int);
        if (ws_size >= needB) {
            int* ws_i   = (int*)d_ws;
            int* counts = ws_i;
            int* start  = ws_i + 32;
            int* cursor = ws_i + 64;
            int* sorted = ws_i + 96;
            hipMemsetAsync(counts, 0, 96 * sizeof(int), stream);
            hist_kernel<<<512, 256, 0, stream>>>(e_kernel, E, counts);
            scan_kernel<<<1, 64, 0, stream>>>(counts, K0, start, cursor);
            scatter_kernel<<<(E + 255) / 256, 256, 0, stream>>>(e_kernel, E, cursor, sorted);
            dim3 grid(64, K0);
            mp_bucket_kernel<<<grid, 256, 0, stream>>>(W, ref, e_ref, e_query, e_weight,
                                                       sorted, start, counts, out);
        }
    }
}

// Round 4
// 369.423 us; speedup vs baseline: 2.0788x; 1.2162x over previous
//
#include <hip/hip_runtime.h>

#define DIN 64
#define DOUT 64
#define MAXK 32

typedef __bf16 bf16x8 __attribute__((ext_vector_type(8)));
typedef float  f32x4  __attribute__((ext_vector_type(4)));

static __device__ inline unsigned short f2b(float x) {
    return __builtin_bit_cast(unsigned short, (__bf16)x);
}
static __device__ inline float b2f(unsigned short u) {
    return __uint_as_float(((unsigned int)u) << 16);
}

// ---------------- conversions ----------------

// W[k][d1][d2] fp32 -> frag-major bf16: Wt[k][t][h][lane][j]
//   lane = quad*16 + col; frag elem = W[k][d1 = h*32 + quad*8 + j][d2 = t*16 + col]
// A-frag load in phaseA becomes base + lane*16B (fully coalesced).
__global__ void conv_w_kernel(const float* __restrict__ W,
                              unsigned short* __restrict__ Wt, int total) {
    int i = blockIdx.x * blockDim.x + threadIdx.x;
    if (i < total) {
        int j    = i & 7;
        int lane = (i >> 3) & 63;
        int h    = (i >> 9) & 1;
        int t    = (i >> 10) & 3;
        int k    = i >> 12;
        int col  = lane & 15;
        int quad = lane >> 4;
        int d1 = h * 32 + quad * 8 + j;
        int d2 = t * 16 + col;
        Wt[i] = f2b(W[(k * 64 + d1) * 64 + d2]);
    }
}

// ---------------- Phase A: dense transform GEMM (bf16 MFMA) ----------------
// T layout: [k][N][d2].  T[k][n][d2] = sum_d1 ref[n][d1] * W[k][d1][d2]
// MFMA roles: A = W^T (M=d2, K=d1), B = ref (K=d1, N=n).
// Epilogue: C-frags -> per-wave LDS tile (16 rows x 128B, stride 144) ->
// linear read-back -> two coalesced global_store_dwordx4 per lane (2KB/wave).

__global__ __launch_bounds__(256) void phaseA_kernel(
    const float* __restrict__ ref,             // [N][64] fp32
    const unsigned short* __restrict__ Wt,     // frag-major, see conv_w
    unsigned short* __restrict__ T,            // [K0][N][64] bf16
    int K0, int Nn)
{
    const int lane = threadIdx.x & 63;
    const int wid  = threadIdx.x >> 6;
    const int col  = lane & 15;
    const int quad = lane >> 4;
    const int n0   = blockIdx.x * 64 + wid * 16;   // 16 rows per wave
    const int row  = n0 + col;

    __shared__ __align__(16) char ldsbuf[4][16 * 144];
    char* buf = ldsbuf[wid];

    // B frag (resident): lane holds ref[row][d1 = quad*8 + j] (two halves of K)
    const float* rp = ref + (size_t)row * 64;
    f32x4 r0 = *reinterpret_cast<const f32x4*>(rp + quad * 8);
    f32x4 r1 = *reinterpret_cast<const f32x4*>(rp + quad * 8 + 4);
    f32x4 r2 = *reinterpret_cast<const f32x4*>(rp + 32 + quad * 8);
    f32x4 r3 = *reinterpret_cast<const f32x4*>(rp + 32 + quad * 8 + 4);
    bf16x8 b0, b1;
    #pragma unroll
    for (int i = 0; i < 4; ++i) {
        b0[i]     = (__bf16)r0[i];
        b0[4 + i] = (__bf16)r1[i];
        b1[i]     = (__bf16)r2[i];
        b1[4 + i] = (__bf16)r3[i];
    }

    const int rrow = lane >> 2;          // epilogue read-back row
    const int rq   = lane & 3;

    for (int k = 0; k < K0; ++k) {
        const unsigned short* Wk = Wt + (size_t)k * 4096;
        #pragma unroll
        for (int t = 0; t < 4; ++t) {
            // coalesced A-frag loads: lane*16B
            const unsigned short* ap = Wk + (size_t)t * 1024 + lane * 8;
            bf16x8 a0 = *reinterpret_cast<const bf16x8*>(ap);
            bf16x8 a1 = *reinterpret_cast<const bf16x8*>(ap + 512);
            f32x4 c = {0.f, 0.f, 0.f, 0.f};
            c = __builtin_amdgcn_mfma_f32_16x16x32_bf16(a0, b0, c, 0, 0, 0);
            c = __builtin_amdgcn_mfma_f32_16x16x32_bf16(a1, b1, c, 0, 0, 0);
            // lane holds T[k][row][t*16 + quad*4 + r] -> stage 8B into LDS
            unsigned int lo = (unsigned int)f2b(c[0]) | ((unsigned int)f2b(c[1]) << 16);
            unsigned int hi = (unsigned int)f2b(c[2]) | ((unsigned int)f2b(c[3]) << 16);
            *reinterpret_cast<uint2*>(buf + col * 144 + t * 32 + quad * 8) =
                make_uint2(lo, hi);
        }
        // read back linearly (same wave, LDS unit is in-order per wave)
        uint4 v0 = *reinterpret_cast<const uint4*>(buf + rrow * 144 + rq * 32);
        uint4 v1 = *reinterpret_cast<const uint4*>(buf + rrow * 144 + rq * 32 + 16);
        size_t gbase = ((size_t)k * Nn + n0 + rrow) * 64 + rq * 16;
        *reinterpret_cast<uint4*>(T + gbase)     = v0;
        *reinterpret_cast<uint4*>(T + gbase + 8) = v1;
    }
}

// ---------------- query counting sort ----------------

__global__ void qhist_kernel(const int* __restrict__ eq, int E, int* __restrict__ qcount) {
    int stride = gridDim.x * blockDim.x;
    for (int i = blockIdx.x * blockDim.x + threadIdx.x; i < E; i += stride)
        atomicAdd(&qcount[eq[i]], 1);
}

__global__ void scan1_kernel(const int* __restrict__ qcount, int* __restrict__ qstart,
                             int* __restrict__ bsum) {
    __shared__ int sh[256];
    int t = threadIdx.x;
    int gid = blockIdx.x * 256 + t;
    int v = qcount[gid];
    sh[t] = v;
    __syncthreads();
    #pragma unroll
    for (int o = 1; o < 256; o <<= 1) {
        int x = (t >= o) ? sh[t - o] : 0;
        __syncthreads();
        sh[t] += x;
        __syncthreads();
    }
    qstart[gid] = sh[t] - v;
    if (t == 255) bsum[blockIdx.x] = sh[255];
}

__global__ void scan2_kernel(int* __restrict__ bsum, int nb) {
    __shared__ int sh[256];
    int t = threadIdx.x;
    int v = (t < nb) ? bsum[t] : 0;
    sh[t] = v;
    __syncthreads();
    #pragma unroll
    for (int o = 1; o < 256; o <<= 1) {
        int x = (t >= o) ? sh[t - o] : 0;
        __syncthreads();
        sh[t] += x;
        __syncthreads();
    }
    if (t < nb) bsum[t] = sh[t] - v;
}

__global__ void scan3_kernel(int* __restrict__ qstart, int* __restrict__ qcursor,
                             const int* __restrict__ bsum, int M, int E) {
    int gid = blockIdx.x * 256 + threadIdx.x;
    int v = qstart[gid] + bsum[blockIdx.x];
    qstart[gid] = v;
    qcursor[gid] = v;
    if (gid == 0) qstart[M] = E;
}

// per-edge records in query-sorted order, packed 8B: {r | k<<16, w_bits}
__global__ void qscatter_kernel(const int* __restrict__ eq, const int* __restrict__ er,
                                const int* __restrict__ ek, const float* __restrict__ ew,
                                int E, int* __restrict__ qcursor, uint2* __restrict__ rec) {
    int i = blockIdx.x * blockDim.x + threadIdx.x;
    if (i < E) {
        int q = eq[i];
        int slot = atomicAdd(&qcursor[q], 1);
        rec[slot] = make_uint2((unsigned int)er[i] | ((unsigned int)ek[i] << 16),
                               __float_as_uint(ew[i]));
    }
}

// ---------------- Phase B: per-query gather-accumulate (no atomics) ----------------

__global__ __launch_bounds__(256) void phaseB_kernel(
    const unsigned short* __restrict__ T,    // [K0][N][64] bf16
    const uint2* __restrict__ rec,
    const int* __restrict__ qstart,
    float* __restrict__ out, int Nn)
{
    const int lane = threadIdx.x & 63;
    const int wid  = threadIdx.x >> 6;
    const int q    = blockIdx.x * 4 + wid;

    int beg = qstart[q];
    int end = qstart[q + 1];
    float acc = 0.f;

    int j = beg;
    for (; j + 3 < end; j += 4) {
        uint2 v0 = rec[j];
        uint2 v1 = rec[j + 1];
        uint2 v2 = rec[j + 2];
        uint2 v3 = rec[j + 3];
        unsigned m0 = __builtin_amdgcn_readfirstlane(v0.x);
        unsigned m1 = __builtin_amdgcn_readfirstlane(v1.x);
        unsigned m2 = __builtin_amdgcn_readfirstlane(v2.x);
        unsigned m3 = __builtin_amdgcn_readfirstlane(v3.x);
        float w0 = __uint_as_float(__builtin_amdgcn_readfirstlane(v0.y));
        float w1 = __uint_as_float(__builtin_amdgcn_readfirstlane(v1.y));
        float w2 = __uint_as_float(__builtin_amdgcn_readfirstlane(v2.y));
        float w3 = __uint_as_float(__builtin_amdgcn_readfirstlane(v3.y));
        unsigned short t0 = T[((size_t)(m0 >> 16) * Nn + (m0 & 0xFFFFu)) * 64 + lane];
        unsigned short t1 = T[((size_t)(m1 >> 16) * Nn + (m1 & 0xFFFFu)) * 64 + lane];
        unsigned short t2 = T[((size_t)(m2 >> 16) * Nn + (m2 & 0xFFFFu)) * 64 + lane];
        unsigned short t3 = T[((size_t)(m3 >> 16) * Nn + (m3 & 0xFFFFu)) * 64 + lane];
        acc = fmaf(w0, b2f(t0), acc);
        acc = fmaf(w1, b2f(t1), acc);
        acc = fmaf(w2, b2f(t2), acc);
        acc = fmaf(w3, b2f(t3), acc);
    }
    for (; j < end; ++j) {
        uint2 v0 = rec[j];
        unsigned m0 = __builtin_amdgcn_readfirstlane(v0.x);
        float w0 = __uint_as_float(__builtin_amdgcn_readfirstlane(v0.y));
        acc = fmaf(w0, b2f(T[((size_t)(m0 >> 16) * Nn + (m0 & 0xFFFFu)) * 64 + lane]), acc);
    }
    out[(size_t)q * 64 + lane] = acc;
}

// ================= fallback path (round-1): kernel-bucketed fp32 =================

__global__ void hist_kernel(const int* __restrict__ ek, int E, int* __restrict__ counts) {
    __shared__ int l[MAXK];
    if (threadIdx.x < MAXK) l[threadIdx.x] = 0;
    __syncthreads();
    int stride = gridDim.x * blockDim.x;
    for (int i = blockIdx.x * blockDim.x + threadIdx.x; i < E; i += stride)
        atomicAdd(&l[ek[i]], 1);
    __syncthreads();
    if (threadIdx.x < MAXK) {
        int v = l[threadIdx.x];
        if (v) atomicAdd(&counts[threadIdx.x], v);
    }
}

__global__ void scan_kernel(const int* __restrict__ counts, int K,
                            int* __restrict__ start, int* __restrict__ cursor) {
    if (threadIdx.x == 0 && blockIdx.x == 0) {
        int acc = 0;
        for (int k = 0; k < K; ++k) {
            start[k] = acc;
            cursor[k] = acc;
            acc += counts[k];
        }
    }
}

__global__ void scatter_kernel(const int* __restrict__ ek, int E,
                               int* __restrict__ cursor, int* __restrict__ sorted) {
    __shared__ int lcnt[MAXK], lbase[MAXK], lpos[MAXK];
    if (threadIdx.x < MAXK) { lcnt[threadIdx.x] = 0; lpos[threadIdx.x] = 0; }
    __syncthreads();
    int i = blockIdx.x * blockDim.x + threadIdx.x;
    int k = 0;
    bool valid = (i < E);
    if (valid) { k = ek[i]; atomicAdd(&lcnt[k], 1); }
    __syncthreads();
    if (threadIdx.x < MAXK) {
        int v = lcnt[threadIdx.x];
        if (v) lbase[threadIdx.x] = atomicAdd(&cursor[threadIdx.x], v);
    }
    __syncthreads();
    if (valid) {
        int slot = lbase[k] + atomicAdd(&lpos[k], 1);
        sorted[slot] = i;
    }
}

__global__ __launch_bounds__(256) void mp_bucket_kernel(
    const float* __restrict__ W, const float* __restrict__ ref,
    const int* __restrict__ e_ref, const int* __restrict__ e_query,
    const float* __restrict__ e_weight, const int* __restrict__ sorted,
    const int* __restrict__ start, const int* __restrict__ counts,
    float* __restrict__ out)
{
    const int k = blockIdx.y;
    const int lane = threadIdx.x & 63;
    const int wid = threadIdx.x >> 6;

    float wreg[DIN];
    const float* Wk = W + k * DIN * DOUT;
    #pragma unroll
    for (int d = 0; d < DIN; ++d) wreg[d] = Wk[d * DOUT + lane];

    const int s = start[k];
    const int c = counts[k];
    const int nwaves = gridDim.x * 4;

    for (int i = blockIdx.x * 4 + wid; i < c; i += nwaves) {
        int eid = __builtin_amdgcn_readfirstlane(sorted[s + i]);
        int r = e_ref[eid];
        int q = e_query[eid];
        float w = e_weight[eid];
        const float* row = ref + r * DIN;
        float a0 = 0.f, a1 = 0.f, a2 = 0.f, a3 = 0.f;
        #pragma unroll
        for (int d = 0; d < DIN; d += 4) {
            a0 += row[d + 0] * wreg[d + 0];
            a1 += row[d + 1] * wreg[d + 1];
            a2 += row[d + 2] * wreg[d + 2];
            a3 += row[d + 3] * wreg[d + 3];
        }
        atomicAdd(&out[q * DOUT + lane], ((a0 + a1) + (a2 + a3)) * w);
    }
}

// =================================================================================

extern "C" void kernel_launch(void* const* d_in, const int* in_sizes, int n_in,
                              void* d_out, int out_size, void* d_ws, size_t ws_size,
                              hipStream_t stream) {
    const float* W        = (const float*)d_in[0];   // [K0, 64, 64]
    const float* ref      = (const float*)d_in[1];   // [N, 64]
    const int*   e_kernel = (const int*)d_in[2];     // [E]
    const int*   e_ref    = (const int*)d_in[3];     // [E]
    const int*   e_query  = (const int*)d_in[4];     // [E]
    const float* e_weight = (const float*)d_in[6];   // [E]

    const int K0 = in_sizes[0] / (DIN * DOUT);
    const int N  = in_sizes[1] / DIN;
    const int E  = in_sizes[2];
    const int M  = out_size / DOUT;
    const int KD = K0 * 64;

    float* out = (float*)d_out;

    // ---- plan A workspace carve ----
    size_t off = 0;
    auto alloc = [&](size_t bytes, size_t align) {
        off = (off + align - 1) / align * align;
        size_t r = off; off += bytes; return r;
    };
    size_t o_rec     = alloc((size_t)E * 8, 16);
    size_t o_qstart  = alloc((size_t)(M + 1) * 4, 4);
    size_t o_qcursor = alloc((size_t)M * 4, 4);
    size_t o_bsum    = alloc(1024 * 4, 4);
    size_t o_wt      = alloc((size_t)K0 * 4096 * 2, 16);
    size_t o_T       = alloc((size_t)N * KD * 2, 16);
    size_t needA = off;

    int nb = (M + 255) / 256;
    bool planA_ok = (ws_size >= needA) && (M % 256 == 0) && (nb <= 256) &&
                    (N % 64 == 0) && (N <= 65536) && (K0 <= 64);

    if (planA_ok) {
        char* ws = (char*)d_ws;
        uint2* rec           = (uint2*)(ws + o_rec);
        int*  qstart         = (int*)(ws + o_qstart);
        int*  qcursor        = (int*)(ws + o_qcursor);
        int*  bsum           = (int*)(ws + o_bsum);
        unsigned short* Wt   = (unsigned short*)(ws + o_wt);
        unsigned short* T    = (unsigned short*)(ws + o_T);

        conv_w_kernel<<<(K0 * 4096 + 255) / 256, 256, 0, stream>>>(W, Wt, K0 * 4096);

        hipMemsetAsync(qcursor, 0, (size_t)M * 4, stream);
        qhist_kernel<<<1024, 256, 0, stream>>>(e_query, E, qcursor);
        scan1_kernel<<<nb, 256, 0, stream>>>(qcursor, qstart, bsum);
        scan2_kernel<<<1, 256, 0, stream>>>(bsum, nb);
        scan3_kernel<<<nb, 256, 0, stream>>>(qstart, qcursor, bsum, M, E);
        qscatter_kernel<<<(E + 255) / 256, 256, 0, stream>>>(e_query, e_ref, e_kernel,
                                                             e_weight, E, qcursor, rec);

        phaseA_kernel<<<N / 64, 256, 0, stream>>>(ref, Wt, T, K0, N);

        phaseB_kernel<<<M / 4, 256, 0, stream>>>(T, rec, qstart, out, N);
    } else {
        hipMemsetAsync(out, 0, (size_t)out_size * sizeof(float), stream);
        size_t needB = (size_t)(96 + E) * sizeof(int);
        if (ws_size >= needB) {
            int* ws_i   = (int*)d_ws;
            int* counts = ws_i;
            int* start  = ws_i + 32;
            int* cursor = ws_i + 64;
            int* sorted = ws_i + 96;
            hipMemsetAsync(counts, 0, 96 * sizeof(int), stream);
            hist_kernel<<<512, 256, 0, stream>>>(e_kernel, E, counts);
            scan_kernel<<<1, 64, 0, stream>>>(counts, K0, start, cursor);
            scatter_kernel<<<(E + 255) / 256, 256, 0, stream>>>(e_kernel, E, cursor, sorted);
            dim3 grid(64, K0);
            mp_bucket_kernel<<<grid, 256, 0, stream>>>(W, ref, e_ref, e_query, e_weight,
                                                       sorted, start, counts, out);
        }
    }
}

// Round 5
// 292.952 us; speedup vs baseline: 2.6215x; 1.2610x over previous
//
#include <hip/hip_runtime.h>

#define DIN 64
#define DOUT 64
#define MAXK 32

typedef __bf16 bf16x8 __attribute__((ext_vector_type(8)));
typedef float  f32x4  __attribute__((ext_vector_type(4)));

static __device__ inline unsigned short f2b(float x) {
    return __builtin_bit_cast(unsigned short, (__bf16)x);
}
static __device__ inline float b2f(unsigned short u) {
    return __uint_as_float(((unsigned int)u) << 16);
}

// ---------------- conversions ----------------

// W[k][d1][d2] fp32 -> frag-major bf16: Wt[k][t][h][lane][j]
__global__ void conv_w_kernel(const float* __restrict__ W,
                              unsigned short* __restrict__ Wt, int total) {
    int i = blockIdx.x * blockDim.x + threadIdx.x;
    if (i < total) {
        int j    = i & 7;
        int lane = (i >> 3) & 63;
        int h    = (i >> 9) & 1;
        int t    = (i >> 10) & 3;
        int k    = i >> 12;
        int col  = lane & 15;
        int quad = lane >> 4;
        int d1 = h * 32 + quad * 8 + j;
        int d2 = t * 16 + col;
        Wt[i] = f2b(W[(k * 64 + d1) * 64 + d2]);
    }
}

// ---------------- Phase A: dense transform GEMM (bf16 MFMA) ----------------
// T layout: [k][N][d2]; epilogue via LDS transpose -> coalesced 16B stores.

__global__ __launch_bounds__(256) void phaseA_kernel(
    const float* __restrict__ ref,
    const unsigned short* __restrict__ Wt,
    unsigned short* __restrict__ T,
    int K0, int Nn)
{
    const int lane = threadIdx.x & 63;
    const int wid  = threadIdx.x >> 6;
    const int col  = lane & 15;
    const int quad = lane >> 4;
    const int n0   = blockIdx.x * 64 + wid * 16;
    const int row  = n0 + col;

    __shared__ __align__(16) char ldsbuf[4][16 * 144];
    char* buf = ldsbuf[wid];

    const float* rp = ref + (size_t)row * 64;
    f32x4 r0 = *reinterpret_cast<const f32x4*>(rp + quad * 8);
    f32x4 r1 = *reinterpret_cast<const f32x4*>(rp + quad * 8 + 4);
    f32x4 r2 = *reinterpret_cast<const f32x4*>(rp + 32 + quad * 8);
    f32x4 r3 = *reinterpret_cast<const f32x4*>(rp + 32 + quad * 8 + 4);
    bf16x8 b0, b1;
    #pragma unroll
    for (int i = 0; i < 4; ++i) {
        b0[i]     = (__bf16)r0[i];
        b0[4 + i] = (__bf16)r1[i];
        b1[i]     = (__bf16)r2[i];
        b1[4 + i] = (__bf16)r3[i];
    }

    const int rrow = lane >> 2;
    const int rq   = lane & 3;

    for (int k = 0; k < K0; ++k) {
        const unsigned short* Wk = Wt + (size_t)k * 4096;
        #pragma unroll
        for (int t = 0; t < 4; ++t) {
            const unsigned short* ap = Wk + (size_t)t * 1024 + lane * 8;
            bf16x8 a0 = *reinterpret_cast<const bf16x8*>(ap);
            bf16x8 a1 = *reinterpret_cast<const bf16x8*>(ap + 512);
            f32x4 c = {0.f, 0.f, 0.f, 0.f};
            c = __builtin_amdgcn_mfma_f32_16x16x32_bf16(a0, b0, c, 0, 0, 0);
            c = __builtin_amdgcn_mfma_f32_16x16x32_bf16(a1, b1, c, 0, 0, 0);
            unsigned int lo = (unsigned int)f2b(c[0]) | ((unsigned int)f2b(c[1]) << 16);
            unsigned int hi = (unsigned int)f2b(c[2]) | ((unsigned int)f2b(c[3]) << 16);
            *reinterpret_cast<uint2*>(buf + col * 144 + t * 32 + quad * 8) =
                make_uint2(lo, hi);
        }
        uint4 v0 = *reinterpret_cast<const uint4*>(buf + rrow * 144 + rq * 32);
        uint4 v1 = *reinterpret_cast<const uint4*>(buf + rrow * 144 + rq * 32 + 16);
        size_t gbase = ((size_t)k * Nn + n0 + rrow) * 64 + rq * 16;
        *reinterpret_cast<uint4*>(T + gbase)     = v0;
        *reinterpret_cast<uint4*>(T + gbase + 8) = v1;
    }
}

// ---------------- 2-level query bucket sort ----------------
// Coarse bucket = q >> 8 (NB = M/256 buckets, NB <= 256); fine = q & 255.
// Payload 8B: {r | k<<16 | qlo<<21, w_bits}   (needs N<=65536, K0<=32)

__global__ void p1_hist_kernel(const int* __restrict__ eq, int E,
                               int* __restrict__ qcount) {
    __shared__ int l[256];
    l[threadIdx.x] = 0;
    __syncthreads();
    int stride = gridDim.x * blockDim.x;
    for (int i = blockIdx.x * blockDim.x + threadIdx.x; i < E; i += stride)
        atomicAdd(&l[((unsigned)eq[i]) >> 8], 1);
    __syncthreads();
    int v = l[threadIdx.x];
    if (v) atomicAdd(&qcount[threadIdx.x], v);
}

__global__ void p1_scan_kernel(const int* __restrict__ qcount,
                               int* __restrict__ gbase, int* __restrict__ gcursor,
                               int* __restrict__ qstart, int NB, int M, int E) {
    __shared__ int sh[256];
    int t = threadIdx.x;
    int v = (t < NB) ? qcount[t] : 0;
    sh[t] = v;
    __syncthreads();
    #pragma unroll
    for (int o = 1; o < 256; o <<= 1) {
        int x = (t >= o) ? sh[t - o] : 0;
        __syncthreads();
        sh[t] += x;
        __syncthreads();
    }
    int ex = sh[t] - v;
    if (t < NB) { gbase[t] = ex; gcursor[t] = ex; }
    if (t == 0) qstart[M] = E;
}

// block-aggregated scatter into coarse buckets; writes are contiguous runs
// within each block's reserved range -> L2 write-combines to full lines.
__global__ __launch_bounds__(256) void p1_scatter_kernel(
    const int* __restrict__ eq, const int* __restrict__ er,
    const int* __restrict__ ek, const float* __restrict__ ew,
    int E, int* __restrict__ gcursor, uint2* __restrict__ tmp)
{
    __shared__ int bin[256];
    __shared__ int base[256];
    const int t = threadIdx.x;
    bin[t] = 0;
    __syncthreads();
    const int i0 = blockIdx.x * 4096;
    unsigned key[16];
    unsigned rank[16];
    uint2 pay[16];
    #pragma unroll
    for (int u = 0; u < 16; ++u) {
        int i = i0 + u * 256 + t;
        if (i < E) {
            int q = eq[i];
            unsigned b = ((unsigned)q) >> 8;
            key[u] = b;
            rank[u] = atomicAdd(&bin[b], 1);
            pay[u] = make_uint2((unsigned)er[i] | ((unsigned)ek[i] << 16) |
                                ((unsigned)(q & 255) << 21),
                                __float_as_uint(ew[i]));
        } else {
            key[u] = 0xFFFFFFFFu;
        }
    }
    __syncthreads();
    int c = bin[t];
    if (c) base[t] = atomicAdd(&gcursor[t], c);
    __syncthreads();
    #pragma unroll
    for (int u = 0; u < 16; ++u) {
        if (key[u] != 0xFFFFFFFFu)
            tmp[(size_t)base[key[u]] + rank[u]] = pay[u];
    }
}

// per-coarse-bucket fine sort + qstart emission; scatter confined to the
// bucket's ~48KB segment -> L2-combined.
__global__ __launch_bounds__(256) void p2_kernel(
    const uint2* __restrict__ tmp, const int* __restrict__ gbase,
    const int* __restrict__ qcount, uint2* __restrict__ rec,
    int* __restrict__ qstart)
{
    __shared__ int fine[256];
    __shared__ int foff[256];
    const int b = blockIdx.x;
    const int t = threadIdx.x;
    const int s = gbase[b];
    const int L = qcount[b];
    fine[t] = 0;
    __syncthreads();
    for (int i = t; i < L; i += 256)
        atomicAdd(&fine[(tmp[s + i].x >> 21) & 255], 1);
    __syncthreads();
    int v = fine[t];
    __syncthreads();
    #pragma unroll
    for (int o = 1; o < 256; o <<= 1) {
        int x = (t >= o) ? fine[t - o] : 0;
        __syncthreads();
        fine[t] += x;
        __syncthreads();
    }
    foff[t] = fine[t] - v;
    qstart[b * 256 + t] = s + foff[t];
    __syncthreads();
    fine[t] = 0;
    __syncthreads();
    for (int i = t; i < L; i += 256) {
        uint2 p = tmp[s + i];
        unsigned fb = (p.x >> 21) & 255;
        int r = atomicAdd(&fine[fb], 1);
        rec[(size_t)s + foff[fb] + r] = p;
    }
}

// ---------------- Phase B: per-query gather-accumulate (no atomics) ----------------

__global__ __launch_bounds__(256) void phaseB_kernel(
    const unsigned short* __restrict__ T,    // [K0][N][64] bf16
    const uint2* __restrict__ rec,
    const int* __restrict__ qstart,
    float* __restrict__ out, int Nn)
{
    const int lane = threadIdx.x & 63;
    const int wid  = threadIdx.x >> 6;
    const int q    = blockIdx.x * 4 + wid;

    int beg = qstart[q];
    int end = qstart[q + 1];
    float acc = 0.f;

    int j = beg;
    for (; j + 3 < end; j += 4) {
        uint2 v0 = rec[j];
        uint2 v1 = rec[j + 1];
        uint2 v2 = rec[j + 2];
        uint2 v3 = rec[j + 3];
        unsigned m0 = __builtin_amdgcn_readfirstlane(v0.x);
        unsigned m1 = __builtin_amdgcn_readfirstlane(v1.x);
        unsigned m2 = __builtin_amdgcn_readfirstlane(v2.x);
        unsigned m3 = __builtin_amdgcn_readfirstlane(v3.x);
        float w0 = __uint_as_float(__builtin_amdgcn_readfirstlane(v0.y));
        float w1 = __uint_as_float(__builtin_amdgcn_readfirstlane(v1.y));
        float w2 = __uint_as_float(__builtin_amdgcn_readfirstlane(v2.y));
        float w3 = __uint_as_float(__builtin_amdgcn_readfirstlane(v3.y));
        unsigned short t0 = T[((size_t)((m0 >> 16) & 31) * Nn + (m0 & 0xFFFFu)) * 64 + lane];
        unsigned short t1 = T[((size_t)((m1 >> 16) & 31) * Nn + (m1 & 0xFFFFu)) * 64 + lane];
        unsigned short t2 = T[((size_t)((m2 >> 16) & 31) * Nn + (m2 & 0xFFFFu)) * 64 + lane];
        unsigned short t3 = T[((size_t)((m3 >> 16) & 31) * Nn + (m3 & 0xFFFFu)) * 64 + lane];
        acc = fmaf(w0, b2f(t0), acc);
        acc = fmaf(w1, b2f(t1), acc);
        acc = fmaf(w2, b2f(t2), acc);
        acc = fmaf(w3, b2f(t3), acc);
    }
    for (; j < end; ++j) {
        uint2 v0 = rec[j];
        unsigned m0 = __builtin_amdgcn_readfirstlane(v0.x);
        float w0 = __uint_as_float(__builtin_amdgcn_readfirstlane(v0.y));
        acc = fmaf(w0, b2f(T[((size_t)((m0 >> 16) & 31) * Nn + (m0 & 0xFFFFu)) * 64 + lane]), acc);
    }
    out[(size_t)q * 64 + lane] = acc;
}

// ================= fallback path (round-1): kernel-bucketed fp32 =================

__global__ void hist_kernel(const int* __restrict__ ek, int E, int* __restrict__ counts) {
    __shared__ int l[MAXK];
    if (threadIdx.x < MAXK) l[threadIdx.x] = 0;
    __syncthreads();
    int stride = gridDim.x * blockDim.x;
    for (int i = blockIdx.x * blockDim.x + threadIdx.x; i < E; i += stride)
        atomicAdd(&l[ek[i]], 1);
    __syncthreads();
    if (threadIdx.x < MAXK) {
        int v = l[threadIdx.x];
        if (v) atomicAdd(&counts[threadIdx.x], v);
    }
}

__global__ void scan_kernel(const int* __restrict__ counts, int K,
                            int* __restrict__ start, int* __restrict__ cursor) {
    if (threadIdx.x == 0 && blockIdx.x == 0) {
        int acc = 0;
        for (int k = 0; k < K; ++k) {
            start[k] = acc;
            cursor[k] = acc;
            acc += counts[k];
        }
    }
}

__global__ void scatter_kernel(const int* __restrict__ ek, int E,
                               int* __restrict__ cursor, int* __restrict__ sorted) {
    __shared__ int lcnt[MAXK], lbase[MAXK], lpos[MAXK];
    if (threadIdx.x < MAXK) { lcnt[threadIdx.x] = 0; lpos[threadIdx.x] = 0; }
    __syncthreads();
    int i = blockIdx.x * blockDim.x + threadIdx.x;
    int k = 0;
    bool valid = (i < E);
    if (valid) { k = ek[i]; atomicAdd(&lcnt[k], 1); }
    __syncthreads();
    if (threadIdx.x < MAXK) {
        int v = lcnt[threadIdx.x];
        if (v) lbase[threadIdx.x] = atomicAdd(&cursor[threadIdx.x], v);
    }
    __syncthreads();
    if (valid) {
        int slot = lbase[k] + atomicAdd(&lpos[k], 1);
        sorted[slot] = i;
    }
}

__global__ __launch_bounds__(256) void mp_bucket_kernel(
    const float* __restrict__ W, const float* __restrict__ ref,
    const int* __restrict__ e_ref, const int* __restrict__ e_query,
    const float* __restrict__ e_weight, const int* __restrict__ sorted,
    const int* __restrict__ start, const int* __restrict__ counts,
    float* __restrict__ out)
{
    const int k = blockIdx.y;
    const int lane = threadIdx.x & 63;
    const int wid = threadIdx.x >> 6;

    float wreg[DIN];
    const float* Wk = W + k * DIN * DOUT;
    #pragma unroll
    for (int d = 0; d < DIN; ++d) wreg[d] = Wk[d * DOUT + lane];

    const int s = start[k];
    const int c = counts[k];
    const int nwaves = gridDim.x * 4;

    for (int i = blockIdx.x * 4 + wid; i < c; i += nwaves) {
        int eid = __builtin_amdgcn_readfirstlane(sorted[s + i]);
        int r = e_ref[eid];
        int q = e_query[eid];
        float w = e_weight[eid];
        const float* row = ref + r * DIN;
        float a0 = 0.f, a1 = 0.f, a2 = 0.f, a3 = 0.f;
        #pragma unroll
        for (int d = 0; d < DIN; d += 4) {
            a0 += row[d + 0] * wreg[d + 0];
            a1 += row[d + 1] * wreg[d + 1];
            a2 += row[d + 2] * wreg[d + 2];
            a3 += row[d + 3] * wreg[d + 3];
        }
        atomicAdd(&out[q * DOUT + lane], ((a0 + a1) + (a2 + a3)) * w);
    }
}

// =================================================================================

extern "C" void kernel_launch(void* const* d_in, const int* in_sizes, int n_in,
                              void* d_out, int out_size, void* d_ws, size_t ws_size,
                              hipStream_t stream) {
    const float* W        = (const float*)d_in[0];   // [K0, 64, 64]
    const float* ref      = (const float*)d_in[1];   // [N, 64]
    const int*   e_kernel = (const int*)d_in[2];     // [E]
    const int*   e_ref    = (const int*)d_in[3];     // [E]
    const int*   e_query  = (const int*)d_in[4];     // [E]
    const float* e_weight = (const float*)d_in[6];   // [E]

    const int K0 = in_sizes[0] / (DIN * DOUT);
    const int N  = in_sizes[1] / DIN;
    const int E  = in_sizes[2];
    const int M  = out_size / DOUT;
    const int KD = K0 * 64;
    const int NB = M / 256;          // coarse buckets

    float* out = (float*)d_out;

    // ---- plan A workspace carve ----
    size_t off = 0;
    auto alloc = [&](size_t bytes, size_t align) {
        off = (off + align - 1) / align * align;
        size_t r = off; off += bytes; return r;
    };
    size_t o_tmp     = alloc((size_t)E * 8, 16);
    size_t o_rec     = alloc((size_t)E * 8, 16);
    size_t o_qstart  = alloc((size_t)(M + 1) * 4, 4);
    size_t o_qcount  = alloc(256 * 4, 4);
    size_t o_gbase   = alloc(256 * 4, 4);
    size_t o_gcursor = alloc(256 * 4, 4);
    size_t o_wt      = alloc((size_t)K0 * 4096 * 2, 16);
    size_t o_T       = alloc((size_t)N * KD * 2, 16);
    size_t needA = off;

    bool planA_ok = (ws_size >= needA) && (M % 256 == 0) && (NB >= 1) && (NB <= 256) &&
                    (N % 64 == 0) && (N <= 65536) && (K0 <= 32);

    if (planA_ok) {
        char* ws = (char*)d_ws;
        uint2* tmp           = (uint2*)(ws + o_tmp);
        uint2* rec           = (uint2*)(ws + o_rec);
        int*  qstart         = (int*)(ws + o_qstart);
        int*  qcount         = (int*)(ws + o_qcount);
        int*  gbase          = (int*)(ws + o_gbase);
        int*  gcursor        = (int*)(ws + o_gcursor);
        unsigned short* Wt   = (unsigned short*)(ws + o_wt);
        unsigned short* T    = (unsigned short*)(ws + o_T);

        conv_w_kernel<<<(K0 * 4096 + 255) / 256, 256, 0, stream>>>(W, Wt, K0 * 4096);

        hipMemsetAsync(qcount, 0, 256 * 4, stream);
        p1_hist_kernel<<<512, 256, 0, stream>>>(e_query, E, qcount);
        p1_scan_kernel<<<1, 256, 0, stream>>>(qcount, gbase, gcursor, qstart, NB, M, E);
        p1_scatter_kernel<<<(E + 4095) / 4096, 256, 0, stream>>>(e_query, e_ref, e_kernel,
                                                                 e_weight, E, gcursor, tmp);
        p2_kernel<<<NB, 256, 0, stream>>>(tmp, gbase, qcount, rec, qstart);

        phaseA_kernel<<<N / 64, 256, 0, stream>>>(ref, Wt, T, K0, N);

        phaseB_kernel<<<M / 4, 256, 0, stream>>>(T, rec, qstart, out, N);
    } else {
        hipMemsetAsync(out, 0, (size_t)out_size * sizeof(float), stream);
        size_t needB = (size_t)(96 + E) * sizeof(int);
        if (ws_size >= needB) {
            int* ws_i   = (int*)d_ws;
            int* counts = ws_i;
            int* start  = ws_i + 32;
            int* cursor = ws_i + 64;
            int* sorted = ws_i + 96;
            hipMemsetAsync(counts, 0, 96 * sizeof(int), stream);
            hist_kernel<<<512, 256, 0, stream>>>(e_kernel, E, counts);
            scan_kernel<<<1, 64, 0, stream>>>(counts, K0, start, cursor);
            scatter_kernel<<<(E + 255) / 256, 256, 0, stream>>>(e_kernel, E, cursor, sorted);
            dim3 grid(64, K0);
            mp_bucket_kernel<<<grid, 256, 0, stream>>>(W, ref, e_ref, e_query, e_weight,
                                                       sorted, start, counts, out);
        }
    }
}